// Round 15
// baseline (1076.858 us; speedup 1.0000x reference)
//
#include <hip/hip_runtime.h>
#include <hip/hip_bf16.h>

#define N_NODES 100000
#define N_EDGES 300000
#define N_GRAPHS 128
#define NODE_VOCAB 200
#define NODE_DIM 128
#define EDGE_DIM 64
#define K_LAYERS 3

#define SCAN_CHUNK 2048
#define SCAN_NBLK ((N_NODES + SCAN_CHUNK - 1) / SCAN_CHUNK)  // 49
#define GEMM_NB ((N_NODES + 63) / 64)   // 1563
#define AGG_NB ((N_NODES + 19) / 20)    // 5000

typedef unsigned short ushort_t;
typedef __attribute__((ext_vector_type(8))) __bf16 bf16x8;
typedef __attribute__((ext_vector_type(4))) float f32x4;

__device__ inline ushort_t f2bf(float f) {
    unsigned int u = __float_as_uint(f);
    unsigned int r = (u + 0x7fff + ((u >> 16) & 1)) >> 16;
    return (ushort_t)r;
}
__device__ inline float bf2f(ushort_t u) {
    return __uint_as_float(((unsigned int)u) << 16);
}
__device__ inline float bflo(unsigned int u) { return __uint_as_float(u << 16); }
__device__ inline float bfhi(unsigned int u) { return __uint_as_float(u & 0xffff0000u); }

// scal row layout (32 fp32): A-in 0-7, A-out 8-15, C-in 16-23, C-out 24-31.
// within each 8-block: layer-k gate reads cols off(k)+j (j=0..k), off={0,2,4}.
#define MASK_J0 0x15151515u
#define MASK_J1 0x28282828u
#define MASK_J2 0x40404040u

// ---------------- static device scratch ----------------
__device__ ushort_t g_hb[2][2][(size_t)N_NODES * NODE_DIM];  // [side][pp] bf16 node state
__device__ ushort_t g_XWx_b[2][(size_t)N_NODES * 256];       // [side] bf16 [xi | xo]
__device__ ushort_t g_WcatT[K_LAYERS][256 * 128];            // Wcat^T bf16
__device__ ushort_t g_QT[K_LAYERS][32][128];                 // gate-chain vectors
__device__ float g_scal[2][(size_t)N_NODES * 32];            // [side] gate scalars
__device__ float g_bias[8][6];                               // e0 vocab bias
__device__ int  g_evoc[2][2 * N_EDGES];                      // [side]
__device__ float g_gsum[2][N_GRAPHS * NODE_DIM];
__device__ float g_cnt[2][N_GRAPHS];
__device__ float g_H[N_GRAPHS * NODE_DIM];
// CSR [side][dir]: dir 0 = in (keyed by col), dir 1 = out (keyed by row)
__device__ int  g_deg[2][2][N_NODES];
__device__ int  g_off[2][2][N_NODES + 1];
__device__ int  g_cur[2][2][N_NODES];
__device__ int2 g_lst[2][2][N_EDGES];  // (src, voc)
__device__ int  g_bsum[2][2][SCAN_NBLK];
__device__ int  g_boff[2][2][SCAN_NBLK];

// ---------------- zero gsum + QT ----------------
__global__ void zero_misc_kernel() {
    int i = blockIdx.x * 256 + threadIdx.x;
    if (i < 2 * N_GRAPHS * NODE_DIM) ((float*)g_gsum)[i] = 0.f;
    if (i < K_LAYERS * 32 * 128) ((ushort_t*)g_QT)[i] = 0;
}

// ---------------- gate chain setup: 6 blocks = (dir, k) pairs ----------------
__global__ void setup_gates_kernel(const float* __restrict__ Wi0, const float* __restrict__ Wi1,
                                   const float* __restrict__ Wo0, const float* __restrict__ Wo1,
                                   const float* __restrict__ eemb) {
    int b = blockIdx.x;  // 0..5
    int D = b / 3, k = b % 3;
    int t = threadIdx.x;  // 128
    const float* W0 = D ? Wo0 : Wi0;
    const float* W1 = D ? Wo1 : Wi1;
    __shared__ float u[64], un[64];
    if (t < 64) u[t] = W1[k * 64 + t];
    __syncthreads();
    int offk = (k == 0) ? 0 : (k == 1 ? 2 : 4);
    for (int j = k; j >= 0; --j) {
        const float* Wj = W0 + (size_t)j * 320 * 64;
        float qa = 0.f, qc = 0.f;
        for (int m = 0; m < 64; ++m) {
            float um = u[m];
            qa += Wj[t * 64 + m] * um;
            qc += Wj[(192 + t) * 64 + m] * um;
        }
        g_QT[j][(D ? 8 : 0) + offk + j][t] = f2bf(qa);
        g_QT[j][(D ? 24 : 16) + offk + j][t] = f2bf(qc);
        float s = 0.f;
        if (t < 64) {
            for (int m = 0; m < 64; ++m) s += Wj[(128 + t) * 64 + m] * u[m];
        }
        __syncthreads();
        if (t < 64) un[t] = s;
        __syncthreads();
        if (t < 64) u[t] = un[t];
        __syncthreads();
    }
    if (t < 8) {
        float s = 0.f;
        for (int m = 0; m < 64; ++m) s += eemb[t * 64 + m] * u[m];
        g_bias[t][D * 3 + k] = s;
    }
}

// ---------------- assemble Wcat^T for ALL layers ----------------
__global__ void assemble_wcat_all(const float* __restrict__ Wgi, const float* __restrict__ Wgo) {
    int idx = blockIdx.x * 256 + threadIdx.x;
    if (idx >= K_LAYERS * 32768) return;
    int k = idx >> 15;
    int rem = idx & 32767;
    int n = rem >> 7;
    int kd = rem & 127;
    float v = (n < 128) ? Wgi[(size_t)k * 16384 + kd * 128 + n]
                        : Wgo[(size_t)k * 16384 + kd * 128 + (n - 128)];
    g_WcatT[k][n * 128 + kd] = f2bf(v);
}

// ---------------- node argmax + embed, both sides (blockIdx.y) ----------------
__global__ void node_embed_kernel(const float* __restrict__ x_s, const float* __restrict__ x_t,
                                  const float* __restrict__ emb, int N) {
    int side = blockIdx.y;
    const float* x = side ? x_t : x_s;
    int wave = threadIdx.x >> 6;
    int lane = threadIdx.x & 63;
    int n = blockIdx.x * 4 + wave;
    if (n >= N) return;
    const float* xr = x + (size_t)n * NODE_VOCAB;
    float v = xr[lane];
    int idx = lane;
    float nv = xr[lane + 64];
    if (nv > v) { v = nv; idx = lane + 64; }
    nv = xr[lane + 128];
    if (nv > v) { v = nv; idx = lane + 128; }
    if (lane < NODE_VOCAB - 192) {
        nv = xr[lane + 192];
        if (nv > v) { v = nv; idx = lane + 192; }
    }
    #pragma unroll
    for (int off = 32; off; off >>= 1) {
        float ov = __shfl_xor(v, off);
        int oi = __shfl_xor(idx, off);
        if (ov > v || (ov == v && oi < idx)) { v = ov; idx = oi; }
    }
    const float* er = emb + (size_t)idx * NODE_DIM;
    g_hb[side][0][(size_t)n * NODE_DIM + lane] = f2bf(er[lane]);
    g_hb[side][0][(size_t)n * NODE_DIM + 64 + lane] = f2bf(er[64 + lane]);
}

// ---------------- edge argmax -> vocab, both sides ----------------
__global__ void edge_voc_kernel(const float* __restrict__ ea_s, const float* __restrict__ ea_t,
                                int M) {
    int side = blockIdx.y;
    const float* ea = side ? ea_t : ea_s;
    long idx = (long)blockIdx.x * 256 + threadIdx.x;
    if (idx >= M) return;
    const float* ar = ea + idx * 8;
    float4 v0 = *(const float4*)ar;
    float4 v1 = *(const float4*)(ar + 4);
    float vals[8] = {v0.x, v0.y, v0.z, v0.w, v1.x, v1.y, v1.z, v1.w};
    int best = 0;
    float bv = vals[0];
    #pragma unroll
    for (int i = 1; i < 8; ++i)
        if (vals[i] > bv) { bv = vals[i]; best = i; }
    g_evoc[side][idx] = best;
}

// ---------------- CSR build (both sides) ----------------
__global__ void csr_zero_kernel() {
    int i = blockIdx.x * 256 + threadIdx.x;
    if (i < 4 * N_NODES) ((int*)g_deg)[i] = 0;
}

__global__ void csr_count_kernel(const int* __restrict__ ei_s, const int* __restrict__ ei_t,
                                 int E) {
    int side = blockIdx.y;
    const int* ei = side ? ei_t : ei_s;
    int e = blockIdx.x * 256 + threadIdx.x;
    if (e >= E) return;
    atomicAdd(&g_deg[side][0][ei[E + e]], 1);  // in keyed by col
    atomicAdd(&g_deg[side][1][ei[e]], 1);      // out keyed by row
}

__global__ void csr_bsum_kernel() {
    int dir = blockIdx.y, side = blockIdx.z;
    const int* deg = g_deg[side][dir];
    int b = blockIdx.x;
    int t = threadIdx.x;
    int base = b * SCAN_CHUNK;
    int s = 0;
    #pragma unroll
    for (int i = 0; i < SCAN_CHUNK / 256; ++i) {
        int idx = base + i * 256 + t;
        if (idx < N_NODES) s += deg[idx];
    }
    __shared__ int red[256];
    red[t] = s;
    __syncthreads();
    for (int d = 128; d; d >>= 1) {
        if (t < d) red[t] += red[t + d];
        __syncthreads();
    }
    if (t == 0) g_bsum[side][dir][b] = red[0];
}

__global__ void csr_bscan_kernel() {
    int dir = blockIdx.x, side = blockIdx.y;
    int t = threadIdx.x;  // 64
    int v = (t < SCAN_NBLK) ? g_bsum[side][dir][t] : 0;
    int orig = v;
    #pragma unroll
    for (int d = 1; d < 64; d <<= 1) {
        int u = __shfl_up(v, d, 64);
        if (t >= d) v += u;
    }
    if (t < SCAN_NBLK) g_boff[side][dir][t] = v - orig;
}

__global__ void csr_off_kernel(int total) {
    int dir = blockIdx.y, side = blockIdx.z;
    const int* deg = g_deg[side][dir];
    int* off = g_off[side][dir];
    int* cur = g_cur[side][dir];
    int b = blockIdx.x;
    int t = threadIdx.x;
    const int per = SCAN_CHUNK / 256;  // 8
    int lo = b * SCAN_CHUNK + t * per;
    int d8[per];
    int s = 0;
    #pragma unroll
    for (int i = 0; i < per; ++i) {
        int idx = lo + i;
        d8[i] = (idx < N_NODES) ? deg[idx] : 0;
        s += d8[i];
    }
    __shared__ int part[256];
    part[t] = s;
    __syncthreads();
    for (int d = 1; d < 256; d <<= 1) {
        int add = (t >= d) ? part[t - d] : 0;
        __syncthreads();
        part[t] += add;
        __syncthreads();
    }
    int run = g_boff[side][dir][b] + part[t] - s;
    #pragma unroll
    for (int i = 0; i < per; ++i) {
        int idx = lo + i;
        if (idx < N_NODES) {
            off[idx] = run;
            cur[idx] = run;
            run += d8[i];
        }
    }
    if (b == 0 && t == 0) off[N_NODES] = total;
}

__global__ void csr_fill_kernel(const int* __restrict__ ei_s, const int* __restrict__ ei_t,
                                int E) {
    int side = blockIdx.y;
    const int* ei = side ? ei_t : ei_s;
    int e = blockIdx.x * 256 + threadIdx.x;
    if (e >= E) return;
    int r = ei[e], c = ei[E + e];
    int p = atomicAdd(&g_cur[side][0][c], 1);
    g_lst[side][0][p] = make_int2(r, g_evoc[side][e]);
    int q = atomicAdd(&g_cur[side][1][r], 1);
    g_lst[side][1][q] = make_int2(c, g_evoc[side][E + e]);
}

// ================= fused pipeline step: gemm(sideG, layerG) + aggregate(sideA, layerA) =========
__device__ __forceinline__ void gemm_body(int blk, int side, int layer, unsigned int mask,
                                          ushort_t* As, int M) {
    const ushort_t* __restrict__ hb = g_hb[side][layer & 1];
    int m0 = blk * 64;
    int t = threadIdx.x;
    int wave = t >> 6, lane = t & 63;

    for (int idx = t; idx < 1024; idx += 320) {
        int m = idx >> 4, c = idx & 15;
        int gm = m0 + m;
        uint4 v = make_uint4(0u, 0u, 0u, 0u);
        if (gm < M) v = *(const uint4*)(hb + (size_t)gm * 128 + c * 8);
        *(uint4*)&As[m * 128 + ((c * 8) ^ ((m & 7) << 3))] = v;
    }
    __syncthreads();

    int lr = lane & 15, lk = lane >> 4;

    if (wave < 4) {
        int nbase = wave * 64;
        f32x4 acc[4][4];  // [nt][mt], D[n][m]
        #pragma unroll
        for (int i = 0; i < 4; ++i)
            #pragma unroll
            for (int j = 0; j < 4; ++j)
                acc[i][j] = (f32x4){0.f, 0.f, 0.f, 0.f};

        const ushort_t* Bbase = &g_WcatT[layer][0] + (size_t)nbase * 128;
        #pragma unroll
        for (int ks = 0; ks < 4; ++ks) {
            bf16x8 a[4], b[4];
            int ke = ks * 32 + lk * 8;
            #pragma unroll
            for (int mt = 0; mt < 4; ++mt) {
                int row = mt * 16 + lr;
                a[mt] = *(const bf16x8*)&As[row * 128 + (ke ^ ((row & 7) << 3))];
            }
            #pragma unroll
            for (int nt = 0; nt < 4; ++nt)
                b[nt] = *(const bf16x8*)(Bbase + (size_t)(nt * 16 + lr) * 128 + ke);
            #pragma unroll
            for (int nt = 0; nt < 4; ++nt)
                #pragma unroll
                for (int mt = 0; mt < 4; ++mt)
                    acc[nt][mt] = __builtin_amdgcn_mfma_f32_16x16x32_bf16(b[nt], a[mt], acc[nt][mt], 0, 0, 0);
        }

        ushort_t* XW = g_XWx_b[side];
        #pragma unroll
        for (int mt = 0; mt < 4; ++mt) {
            int gm = m0 + mt * 16 + lr;
            if (gm >= M) continue;
            #pragma unroll
            for (int nt = 0; nt < 4; ++nt) {
                int n0 = nbase + nt * 16 + lk * 4;
                f32x4 av = acc[nt][mt];
                uint2 pk;
                pk.x = ((unsigned int)f2bf(av[1]) << 16) | (unsigned int)f2bf(av[0]);
                pk.y = ((unsigned int)f2bf(av[3]) << 16) | (unsigned int)f2bf(av[2]);
                *(uint2*)&XW[(size_t)gm * 256 + n0] = pk;
            }
        }
    } else {
        const ushort_t* QT = &g_QT[layer][0][0];
        f32x4 acc[2][4];
        #pragma unroll
        for (int i = 0; i < 2; ++i)
            #pragma unroll
            for (int j = 0; j < 4; ++j)
                acc[i][j] = (f32x4){0.f, 0.f, 0.f, 0.f};

        #pragma unroll
        for (int ks = 0; ks < 4; ++ks) {
            bf16x8 a[4], b[2];
            int ke = ks * 32 + lk * 8;
            #pragma unroll
            for (int mt = 0; mt < 4; ++mt) {
                int row = mt * 16 + lr;
                a[mt] = *(const bf16x8*)&As[row * 128 + (ke ^ ((row & 7) << 3))];
            }
            #pragma unroll
            for (int nt = 0; nt < 2; ++nt)
                b[nt] = *(const bf16x8*)&QT[(nt * 16 + lr) * 128 + ke];
            #pragma unroll
            for (int nt = 0; nt < 2; ++nt)
                #pragma unroll
                for (int mt = 0; mt < 4; ++mt)
                    acc[nt][mt] = __builtin_amdgcn_mfma_f32_16x16x32_bf16(b[nt], a[mt], acc[nt][mt], 0, 0, 0);
        }

        float* sc = g_scal[side];
        #pragma unroll
        for (int mt = 0; mt < 4; ++mt) {
            int gm = m0 + mt * 16 + lr;
            if (gm >= M) continue;
            #pragma unroll
            for (int nt = 0; nt < 2; ++nt) {
                #pragma unroll
                for (int r = 0; r < 4; ++r) {
                    int colc = nt * 16 + lk * 4 + r;
                    if ((mask >> colc) & 1u)
                        sc[(size_t)gm * 32 + colc] = acc[nt][mt][r];
                }
            }
        }
    }
}

__device__ __forceinline__ void agg_body(int blk, int side, int k,
                                         const float* __restrict__ bgi,
                                         const float* __restrict__ bgo, int N) {
    int t = threadIdx.x;
    int wv = t >> 6;           // 0..4
    int lane = t & 63;
    int grp = lane >> 4, li = lane & 15;
    int n = blk * 20 + wv * 4 + grp;
    bool valid = n < N;
    int cur = k & 1;
    const float* scal = g_scal[side];
    const ushort_t* XW = g_XWx_b[side];

    int pin0 = 0, din = 0, pout0 = 0, dout = 0;
    float cin = 0.f, cout = 0.f;
    if (valid) {
        pin0 = g_off[side][0][n];  din = g_off[side][0][n + 1] - pin0;
        pout0 = g_off[side][1][n]; dout = g_off[side][1][n + 1] - pout0;
        const float* srow = scal + (size_t)n * 32;
        if (k == 0) {
            cin = srow[16]; cout = srow[24];
        } else if (k == 1) {
            cin = srow[18] + srow[19]; cout = srow[26] + srow[27];
        } else {
            cin = srow[20] + srow[21] + srow[22];
            cout = srow[28] + srow[29] + srow[30];
        }
    }
    int tot = din + dout;

    float acc[8];
    {
        float4 b1 = *(const float4*)(bgi + li * 8);
        float4 b2 = *(const float4*)(bgi + li * 8 + 4);
        float4 c1 = *(const float4*)(bgo + li * 8);
        float4 c2 = *(const float4*)(bgo + li * 8 + 4);
        uint4 xv = make_uint4(0u, 0u, 0u, 0u);
        if (valid) xv = *(const uint4*)(g_hb[side][cur] + (size_t)n * 128 + li * 8);
        acc[0] = bflo(xv.x) + b1.x + c1.x;
        acc[1] = bfhi(xv.x) + b1.y + c1.y;
        acc[2] = bflo(xv.y) + b1.z + c1.z;
        acc[3] = bfhi(xv.y) + b1.w + c1.w;
        acc[4] = bflo(xv.z) + b2.x + c2.x;
        acc[5] = bfhi(xv.z) + b2.y + c2.y;
        acc[6] = bflo(xv.w) + b2.z + c2.z;
        acc[7] = bfhi(xv.w) + b2.w + c2.w;
    }

    for (int base = 0; base < tot; base += 16) {
        int cnt = min(16, tot - base);
        float gate = 0.f;
        int sv = 0;
        if (li < cnt) {
            int q = base + li;
            int2 se;
            int dir;
            if (q < din) { se = g_lst[side][0][pin0 + q]; dir = 0; }
            else         { se = g_lst[side][1][pout0 + q - din]; dir = 1; }
            const float* arow = scal + (size_t)se.x * 32 + dir * 8;
            float asum;
            if (k == 0) asum = arow[0];
            else if (k == 1) asum = arow[2] + arow[3];
            else asum = arow[4] + arow[5] + arow[6];
            float s = g_bias[se.y][dir * 3 + k] + asum + (dir ? cout : cin);
            gate = 1.0f / (1.0f + __expf(-s));
            sv = se.x * 2 + dir;
        }
        int e = 0;
        for (; e + 2 <= cnt; e += 2) {
            float w0 = __shfl(gate, grp * 16 + e);
            int a0 = __shfl(sv, grp * 16 + e);
            float w1 = __shfl(gate, grp * 16 + e + 1);
            int a1 = __shfl(sv, grp * 16 + e + 1);
            uint4 p0 = *(const uint4*)(XW + (size_t)(a0 >> 1) * 256 + (a0 & 1) * 128 + li * 8);
            uint4 p1 = *(const uint4*)(XW + (size_t)(a1 >> 1) * 256 + (a1 & 1) * 128 + li * 8);
            acc[0] += w0 * bflo(p0.x) + w1 * bflo(p1.x);
            acc[1] += w0 * bfhi(p0.x) + w1 * bfhi(p1.x);
            acc[2] += w0 * bflo(p0.y) + w1 * bflo(p1.y);
            acc[3] += w0 * bfhi(p0.y) + w1 * bfhi(p1.y);
            acc[4] += w0 * bflo(p0.z) + w1 * bflo(p1.z);
            acc[5] += w0 * bfhi(p0.z) + w1 * bfhi(p1.z);
            acc[6] += w0 * bflo(p0.w) + w1 * bflo(p1.w);
            acc[7] += w0 * bfhi(p0.w) + w1 * bfhi(p1.w);
        }
        if (e < cnt) {
            float w0 = __shfl(gate, grp * 16 + e);
            int a0 = __shfl(sv, grp * 16 + e);
            uint4 p0 = *(const uint4*)(XW + (size_t)(a0 >> 1) * 256 + (a0 & 1) * 128 + li * 8);
            acc[0] += w0 * bflo(p0.x);
            acc[1] += w0 * bfhi(p0.x);
            acc[2] += w0 * bflo(p0.y);
            acc[3] += w0 * bfhi(p0.y);
            acc[4] += w0 * bflo(p0.z);
            acc[5] += w0 * bfhi(p0.z);
            acc[6] += w0 * bflo(p0.w);
            acc[7] += w0 * bfhi(p0.w);
        }
    }

    if (valid) {
        uint4 pk;
        pk.x = ((unsigned int)f2bf(acc[1]) << 16) | (unsigned int)f2bf(acc[0]);
        pk.y = ((unsigned int)f2bf(acc[3]) << 16) | (unsigned int)f2bf(acc[2]);
        pk.z = ((unsigned int)f2bf(acc[5]) << 16) | (unsigned int)f2bf(acc[4]);
        pk.w = ((unsigned int)f2bf(acc[7]) << 16) | (unsigned int)f2bf(acc[6]);
        *(uint4*)(g_hb[side][cur ^ 1] + (size_t)n * 128 + li * 8) = pk;
    }
}

__global__ __launch_bounds__(320) void fused_step(const float* __restrict__ bgi,
                                                  const float* __restrict__ bgo,
                                                  int gemm_side, int gemm_layer,
                                                  unsigned int mask,
                                                  int agg_side, int agg_layer,
                                                  int gemm_nb, int total, int N) {
    __shared__ ushort_t As[64 * 128];  // 16 KB (gemm path only)
    int bid = blockIdx.x;
    int g_before = (int)(((long)bid * gemm_nb) / total);
    int g_next = (int)(((long)(bid + 1) * gemm_nb) / total);
    if (g_next > g_before) {
        gemm_body(g_before, gemm_side, gemm_layer, mask, As, N);
    } else {
        agg_body(bid - g_before, agg_side, agg_layer, bgi, bgo, N);
    }
}

// ---------------- mean-pool partials, both sides ----------------
__global__ void pool_kernel(const int* __restrict__ batch_s, const int* __restrict__ batch_t,
                            int N) {
    int side = blockIdx.y;
    const int* batch = side ? batch_t : batch_s;
    const ushort_t* x = g_hb[side][K_LAYERS & 1];
    float* gsum = g_gsum[side];
    int n0 = blockIdx.x * 128;
    int d = threadIdx.x;
    if (n0 >= N) return;
    int nend = min(n0 + 128, N);
    float acc = 0.f;
    int curg = batch[n0];
    for (int n = n0; n < nend; ++n) {
        int g = batch[n];
        if (g != curg) {
            atomicAdd(&gsum[curg * 128 + d], acc);
            acc = 0.f;
            curg = g;
        }
        acc += bf2f(x[(size_t)n * 128 + d]);
    }
    atomicAdd(&gsum[curg * 128 + d], acc);
}

__global__ void count_kernel(const int* __restrict__ batch_s, const int* __restrict__ batch_t,
                             int N) {
    int side = blockIdx.x;
    const int* batch = side ? batch_t : batch_s;
    int g = threadIdx.x;  // 128
    int lo = 0, hi = N;
    while (lo < hi) { int mid = (lo + hi) >> 1; if (batch[mid] < g) lo = mid + 1; else hi = mid; }
    int a = lo;
    lo = 0; hi = N;
    while (lo < hi) { int mid = (lo + hi) >> 1; if (batch[mid] < g + 1) lo = mid + 1; else hi = mid; }
    g_cnt[side][g] = (float)(lo - a);
}

// ---------------- classifier ----------------
__global__ void hidden_kernel(const float* __restrict__ W0, const float* __restrict__ b0) {
    int g = blockIdx.x;
    int j = threadIdx.x;
    float inv_s = 1.0f / fmaxf(g_cnt[0][g], 1.0f);
    float inv_t = 1.0f / fmaxf(g_cnt[1][g], 1.0f);
    float acc = b0[j];
    for (int k = 0; k < 128; ++k) acc += g_gsum[0][g * 128 + k] * inv_s * W0[k * 128 + j];
    for (int k = 0; k < 128; ++k) acc += g_gsum[1][g * 128 + k] * inv_t * W0[(128 + k) * 128 + j];
    g_H[g * 128 + j] = fmaxf(acc, 0.f);
}

__global__ void loss_kernel(const float* __restrict__ W1, const float* __restrict__ b1,
                            const int* __restrict__ y, float* __restrict__ out) {
    int g = threadIdx.x;
    float l0 = b1[0], l1 = b1[1];
    for (int j = 0; j < 128; ++j) {
        float hv = g_H[g * 128 + j];
        l0 += hv * W1[j * 2 + 0];
        l1 += hv * W1[j * 2 + 1];
    }
    float m = fmaxf(l0, l1);
    float lse = m + logf(expf(l0 - m) + expf(l1 - m));
    float ly = (y[g] == 0) ? l0 : l1;
    float c = -(ly - lse) * (1.0f / (float)N_GRAPHS);
    __shared__ float red[128];
    red[g] = c;
    __syncthreads();
    for (int s = 64; s; s >>= 1) {
        if (g < s) red[g] += red[g + s];
        __syncthreads();
    }
    if (g == 0) out[0] = red[0];
}

extern "C" void kernel_launch(void* const* d_in, const int* in_sizes, int n_in,
                              void* d_out, int out_size, void* d_ws, size_t ws_size,
                              hipStream_t stream) {
    const float* x_s      = (const float*)d_in[0];
    const float* x_t      = (const float*)d_in[1];
    const float* ea_s     = (const float*)d_in[2];
    const float* ea_t     = (const float*)d_in[3];
    const int*   ei_s     = (const int*)d_in[4];
    const int*   ei_t     = (const int*)d_in[5];
    const int*   batch_s  = (const int*)d_in[6];
    const int*   batch_t  = (const int*)d_in[7];
    const int*   y        = (const int*)d_in[8];
    const float* node_emb = (const float*)d_in[9];
    const float* edge_emb = (const float*)d_in[10];
    const float* W_in_0   = (const float*)d_in[11];
    const float* W_in_1   = (const float*)d_in[12];
    const float* W_out_0  = (const float*)d_in[13];
    const float* W_out_1  = (const float*)d_in[14];
    const float* Wg_in    = (const float*)d_in[15];
    const float* bg_in    = (const float*)d_in[16];
    const float* Wg_out   = (const float*)d_in[17];
    const float* bg_out   = (const float*)d_in[18];
    const float* cls_W0   = (const float*)d_in[19];
    const float* cls_b0   = (const float*)d_in[20];
    const float* cls_W1   = (const float*)d_in[21];
    const float* cls_b1   = (const float*)d_in[22];

    const int N = N_NODES, E = N_EDGES;
    static const unsigned int MASKS[3] = {MASK_J0, MASK_J1, MASK_J2};

    zero_misc_kernel<<<(2 * N_GRAPHS * NODE_DIM + 255) / 256, 256, 0, stream>>>();
    setup_gates_kernel<<<6, 128, 0, stream>>>(W_in_0, W_in_1, W_out_0, W_out_1, edge_emb);
    assemble_wcat_all<<<(K_LAYERS * 32768 + 255) / 256, 256, 0, stream>>>(Wg_in, Wg_out);

    node_embed_kernel<<<dim3((N + 3) / 4, 2), 256, 0, stream>>>(x_s, x_t, node_emb, N);
    edge_voc_kernel<<<dim3((2 * E + 255) / 256, 2), 256, 0, stream>>>(ea_s, ea_t, 2 * E);

    csr_zero_kernel<<<(4 * N + 255) / 256, 256, 0, stream>>>();
    csr_count_kernel<<<dim3((E + 255) / 256, 2), 256, 0, stream>>>(ei_s, ei_t, E);
    csr_bsum_kernel<<<dim3(SCAN_NBLK, 2, 2), 256, 0, stream>>>();
    csr_bscan_kernel<<<dim3(2, 2), 64, 0, stream>>>();
    csr_off_kernel<<<dim3(SCAN_NBLK, 2, 2), 256, 0, stream>>>(E);
    csr_fill_kernel<<<dim3((E + 255) / 256, 2), 256, 0, stream>>>(ei_s, ei_t, E);

    const int FULL = GEMM_NB + AGG_NB;
    // step 0: Gemm(s,0)
    fused_step<<<GEMM_NB, 320, 0, stream>>>(bg_in, bg_out, 0, 0, MASKS[0], -1, 0, GEMM_NB,
                                            GEMM_NB, N);
    // step 1: Gemm(t,0) + Agg(s,0)
    fused_step<<<FULL, 320, 0, stream>>>(bg_in, bg_out, 1, 0, MASKS[0], 0, 0, GEMM_NB, FULL, N);
    // step 2: Gemm(s,1) + Agg(t,0)
    fused_step<<<FULL, 320, 0, stream>>>(bg_in, bg_out, 0, 1, MASKS[1], 1, 0, GEMM_NB, FULL, N);
    // step 3: Gemm(t,1) + Agg(s,1)
    fused_step<<<FULL, 320, 0, stream>>>(bg_in + 128, bg_out + 128, 1, 1, MASKS[1], 0, 1,
                                         GEMM_NB, FULL, N);
    // step 4: Gemm(s,2) + Agg(t,1)
    fused_step<<<FULL, 320, 0, stream>>>(bg_in + 128, bg_out + 128, 0, 2, MASKS[2], 1, 1,
                                         GEMM_NB, FULL, N);
    // step 5: Gemm(t,2) + Agg(s,2)
    fused_step<<<FULL, 320, 0, stream>>>(bg_in + 256, bg_out + 256, 1, 2, MASKS[2], 0, 2,
                                         GEMM_NB, FULL, N);
    // step 6: Agg(t,2)
    fused_step<<<AGG_NB, 320, 0, stream>>>(bg_in + 256, bg_out + 256, 0, 0, 0u, 1, 2, 0,
                                           AGG_NB, N);

    pool_kernel<<<dim3((N + 127) / 128, 2), 128, 0, stream>>>(batch_s, batch_t, N);
    count_kernel<<<2, 128, 0, stream>>>(batch_s, batch_t, N);

    hidden_kernel<<<128, 128, 0, stream>>>(cls_W0, cls_b0);
    loss_kernel<<<1, 128, 0, stream>>>(cls_W1, cls_b1, y, (float*)d_out);
}

// Round 16
// 829.037 us; speedup vs baseline: 1.2989x; 1.2989x over previous
//
#include <hip/hip_runtime.h>
#include <hip/hip_bf16.h>

#define N_NODES 100000
#define N_EDGES 300000
#define N_GRAPHS 128
#define NODE_VOCAB 200
#define NODE_DIM 128
#define EDGE_DIM 64
#define K_LAYERS 3

#define SCAN_CHUNK 2048
#define SCAN_NBLK ((N_NODES + SCAN_CHUNK - 1) / SCAN_CHUNK)  // 49
#define GEMM_NB ((N_NODES + 63) / 64)

typedef unsigned short ushort_t;
typedef __attribute__((ext_vector_type(8))) __bf16 bf16x8;
typedef __attribute__((ext_vector_type(4))) float f32x4;

__device__ inline ushort_t f2bf(float f) {
    unsigned int u = __float_as_uint(f);
    unsigned int r = (u + 0x7fff + ((u >> 16) & 1)) >> 16;
    return (ushort_t)r;
}
__device__ inline float bf2f(ushort_t u) {
    return __uint_as_float(((unsigned int)u) << 16);
}
__device__ inline float bflo(unsigned int u) { return __uint_as_float(u << 16); }
__device__ inline float bfhi(unsigned int u) { return __uint_as_float(u & 0xffff0000u); }

// scal row layout (32 fp32): A-in 0-7, A-out 8-15, C-in 16-23, C-out 24-31.
// within each 8-block: layer-k gate reads cols off(k)+j (j=0..k), off={0,2,4}.
#define MASK_J0 0x15151515u
#define MASK_J1 0x28282828u
#define MASK_J2 0x40404040u

// ---------------- static device scratch ----------------
__device__ ushort_t g_hb[2][2][(size_t)N_NODES * NODE_DIM];  // [side][pp] bf16 node state
__device__ ushort_t g_XWx_b[2][(size_t)N_NODES * 256];       // [side] bf16 [xi | xo]
__device__ ushort_t g_WcatT[K_LAYERS][256 * 128];            // Wcat^T bf16
__device__ ushort_t g_QT[K_LAYERS][32][128];                 // gate-chain vectors
__device__ float g_scal[2][(size_t)N_NODES * 32];            // [side] gate scalars
__device__ float g_bias[8][6];                               // e0 vocab bias
__device__ int  g_evoc[2][2 * N_EDGES];                      // [side]
__device__ float g_gsum[2][N_GRAPHS * NODE_DIM];
__device__ float g_cnt[2][N_GRAPHS];
__device__ float g_H[N_GRAPHS * NODE_DIM];
// CSR [side][dir]: dir 0 = in (keyed by col), dir 1 = out (keyed by row)
__device__ int  g_deg[2][2][N_NODES];
__device__ int  g_off[2][2][N_NODES + 1];
__device__ int  g_cur[2][2][N_NODES];
__device__ int2 g_lst[2][2][N_EDGES];  // (src, voc)
__device__ int  g_bsum[2][2][SCAN_NBLK];
__device__ int  g_boff[2][2][SCAN_NBLK];

// ---------------- zero gsum + QT ----------------
__global__ void zero_misc_kernel() {
    int i = blockIdx.x * 256 + threadIdx.x;
    if (i < 2 * N_GRAPHS * NODE_DIM) ((float*)g_gsum)[i] = 0.f;
    if (i < K_LAYERS * 32 * 128) ((ushort_t*)g_QT)[i] = 0;
}

// ---------------- gate chain setup: 6 blocks = (dir, k) pairs ----------------
__global__ void setup_gates_kernel(const float* __restrict__ Wi0, const float* __restrict__ Wi1,
                                   const float* __restrict__ Wo0, const float* __restrict__ Wo1,
                                   const float* __restrict__ eemb) {
    int b = blockIdx.x;  // 0..5
    int D = b / 3, k = b % 3;
    int t = threadIdx.x;  // 128
    const float* W0 = D ? Wo0 : Wi0;
    const float* W1 = D ? Wo1 : Wi1;
    __shared__ float u[64], un[64];
    if (t < 64) u[t] = W1[k * 64 + t];
    __syncthreads();
    int offk = (k == 0) ? 0 : (k == 1 ? 2 : 4);
    for (int j = k; j >= 0; --j) {
        const float* Wj = W0 + (size_t)j * 320 * 64;
        float qa = 0.f, qc = 0.f;
        for (int m = 0; m < 64; ++m) {
            float um = u[m];
            qa += Wj[t * 64 + m] * um;
            qc += Wj[(192 + t) * 64 + m] * um;
        }
        g_QT[j][(D ? 8 : 0) + offk + j][t] = f2bf(qa);
        g_QT[j][(D ? 24 : 16) + offk + j][t] = f2bf(qc);
        float s = 0.f;
        if (t < 64) {
            for (int m = 0; m < 64; ++m) s += Wj[(128 + t) * 64 + m] * u[m];
        }
        __syncthreads();
        if (t < 64) un[t] = s;
        __syncthreads();
        if (t < 64) u[t] = un[t];
        __syncthreads();
    }
    if (t < 8) {
        float s = 0.f;
        for (int m = 0; m < 64; ++m) s += eemb[t * 64 + m] * u[m];
        g_bias[t][D * 3 + k] = s;
    }
}

// ---------------- assemble Wcat^T for ALL layers ----------------
__global__ void assemble_wcat_all(const float* __restrict__ Wgi, const float* __restrict__ Wgo) {
    int idx = blockIdx.x * 256 + threadIdx.x;
    if (idx >= K_LAYERS * 32768) return;
    int k = idx >> 15;
    int rem = idx & 32767;
    int n = rem >> 7;
    int kd = rem & 127;
    float v = (n < 128) ? Wgi[(size_t)k * 16384 + kd * 128 + n]
                        : Wgo[(size_t)k * 16384 + kd * 128 + (n - 128)];
    g_WcatT[k][n * 128 + kd] = f2bf(v);
}

// ---------------- node argmax + embed, both sides (blockIdx.y) ----------------
__global__ void node_embed_kernel(const float* __restrict__ x_s, const float* __restrict__ x_t,
                                  const float* __restrict__ emb, int N) {
    int side = blockIdx.y;
    const float* x = side ? x_t : x_s;
    int wave = threadIdx.x >> 6;
    int lane = threadIdx.x & 63;
    int n = blockIdx.x * 4 + wave;
    if (n >= N) return;
    const float* xr = x + (size_t)n * NODE_VOCAB;
    float v = xr[lane];
    int idx = lane;
    float nv = xr[lane + 64];
    if (nv > v) { v = nv; idx = lane + 64; }
    nv = xr[lane + 128];
    if (nv > v) { v = nv; idx = lane + 128; }
    if (lane < NODE_VOCAB - 192) {
        nv = xr[lane + 192];
        if (nv > v) { v = nv; idx = lane + 192; }
    }
    #pragma unroll
    for (int off = 32; off; off >>= 1) {
        float ov = __shfl_xor(v, off);
        int oi = __shfl_xor(idx, off);
        if (ov > v || (ov == v && oi < idx)) { v = ov; idx = oi; }
    }
    const float* er = emb + (size_t)idx * NODE_DIM;
    g_hb[side][0][(size_t)n * NODE_DIM + lane] = f2bf(er[lane]);
    g_hb[side][0][(size_t)n * NODE_DIM + 64 + lane] = f2bf(er[64 + lane]);
}

// ---------------- edge argmax -> vocab, both sides ----------------
__global__ void edge_voc_kernel(const float* __restrict__ ea_s, const float* __restrict__ ea_t,
                                int M) {
    int side = blockIdx.y;
    const float* ea = side ? ea_t : ea_s;
    long idx = (long)blockIdx.x * 256 + threadIdx.x;
    if (idx >= M) return;
    const float* ar = ea + idx * 8;
    float4 v0 = *(const float4*)ar;
    float4 v1 = *(const float4*)(ar + 4);
    float vals[8] = {v0.x, v0.y, v0.z, v0.w, v1.x, v1.y, v1.z, v1.w};
    int best = 0;
    float bv = vals[0];
    #pragma unroll
    for (int i = 1; i < 8; ++i)
        if (vals[i] > bv) { bv = vals[i]; best = i; }
    g_evoc[side][idx] = best;
}

// ---------------- CSR build (both sides) ----------------
__global__ void csr_zero_kernel() {
    int i = blockIdx.x * 256 + threadIdx.x;
    if (i < 4 * N_NODES) ((int*)g_deg)[i] = 0;
}

__global__ void csr_count_kernel(const int* __restrict__ ei_s, const int* __restrict__ ei_t,
                                 int E) {
    int side = blockIdx.y;
    const int* ei = side ? ei_t : ei_s;
    int e = blockIdx.x * 256 + threadIdx.x;
    if (e >= E) return;
    atomicAdd(&g_deg[side][0][ei[E + e]], 1);  // in keyed by col
    atomicAdd(&g_deg[side][1][ei[e]], 1);      // out keyed by row
}

__global__ void csr_bsum_kernel() {
    int dir = blockIdx.y, side = blockIdx.z;
    const int* deg = g_deg[side][dir];
    int b = blockIdx.x;
    int t = threadIdx.x;
    int base = b * SCAN_CHUNK;
    int s = 0;
    #pragma unroll
    for (int i = 0; i < SCAN_CHUNK / 256; ++i) {
        int idx = base + i * 256 + t;
        if (idx < N_NODES) s += deg[idx];
    }
    __shared__ int red[256];
    red[t] = s;
    __syncthreads();
    for (int d = 128; d; d >>= 1) {
        if (t < d) red[t] += red[t + d];
        __syncthreads();
    }
    if (t == 0) g_bsum[side][dir][b] = red[0];
}

__global__ void csr_bscan_kernel() {
    int dir = blockIdx.x, side = blockIdx.y;
    int t = threadIdx.x;  // 64
    int v = (t < SCAN_NBLK) ? g_bsum[side][dir][t] : 0;
    int orig = v;
    #pragma unroll
    for (int d = 1; d < 64; d <<= 1) {
        int u = __shfl_up(v, d, 64);
        if (t >= d) v += u;
    }
    if (t < SCAN_NBLK) g_boff[side][dir][t] = v - orig;
}

__global__ void csr_off_kernel(int total) {
    int dir = blockIdx.y, side = blockIdx.z;
    const int* deg = g_deg[side][dir];
    int* off = g_off[side][dir];
    int* cur = g_cur[side][dir];
    int b = blockIdx.x;
    int t = threadIdx.x;
    const int per = SCAN_CHUNK / 256;  // 8
    int lo = b * SCAN_CHUNK + t * per;
    int d8[per];
    int s = 0;
    #pragma unroll
    for (int i = 0; i < per; ++i) {
        int idx = lo + i;
        d8[i] = (idx < N_NODES) ? deg[idx] : 0;
        s += d8[i];
    }
    __shared__ int part[256];
    part[t] = s;
    __syncthreads();
    for (int d = 1; d < 256; d <<= 1) {
        int add = (t >= d) ? part[t - d] : 0;
        __syncthreads();
        part[t] += add;
        __syncthreads();
    }
    int run = g_boff[side][dir][b] + part[t] - s;
    #pragma unroll
    for (int i = 0; i < per; ++i) {
        int idx = lo + i;
        if (idx < N_NODES) {
            off[idx] = run;
            cur[idx] = run;
            run += d8[i];
        }
    }
    if (b == 0 && t == 0) off[N_NODES] = total;
}

__global__ void csr_fill_kernel(const int* __restrict__ ei_s, const int* __restrict__ ei_t,
                                int E) {
    int side = blockIdx.y;
    const int* ei = side ? ei_t : ei_s;
    int e = blockIdx.x * 256 + threadIdx.x;
    if (e >= E) return;
    int r = ei[e], c = ei[E + e];
    int p = atomicAdd(&g_cur[side][0][c], 1);
    g_lst[side][0][p] = make_int2(r, g_evoc[side][e]);
    int q = atomicAdd(&g_cur[side][1][r], 1);
    g_lst[side][1][q] = make_int2(c, g_evoc[side][E + e]);
}

// ---- node GEMM via MFMA (swapped operands), both sides via blockIdx.y ----
__global__ __launch_bounds__(320) void gemm_xw_mfma(int layer, unsigned int mask, int M) {
    int side = blockIdx.y;
    const ushort_t* __restrict__ hb = g_hb[side][layer & 1];
    int m0 = blockIdx.x * 64;
    int t = threadIdx.x;
    int wave = t >> 6, lane = t & 63;
    __shared__ ushort_t As[64 * 128];  // 16 KB, XOR-swizzled

    for (int idx = t; idx < 1024; idx += 320) {
        int m = idx >> 4, c = idx & 15;
        int gm = m0 + m;
        uint4 v = make_uint4(0u, 0u, 0u, 0u);
        if (gm < M) v = *(const uint4*)(hb + (size_t)gm * 128 + c * 8);
        *(uint4*)&As[m * 128 + ((c * 8) ^ ((m & 7) << 3))] = v;
    }
    __syncthreads();

    int lr = lane & 15, lk = lane >> 4;

    if (wave < 4) {
        int nbase = wave * 64;
        f32x4 acc[4][4];  // [nt][mt], D[n][m]
        #pragma unroll
        for (int i = 0; i < 4; ++i)
            #pragma unroll
            for (int j = 0; j < 4; ++j)
                acc[i][j] = (f32x4){0.f, 0.f, 0.f, 0.f};

        const ushort_t* Bbase = &g_WcatT[layer][0] + (size_t)nbase * 128;
        #pragma unroll
        for (int ks = 0; ks < 4; ++ks) {
            bf16x8 a[4], b[4];
            int ke = ks * 32 + lk * 8;
            #pragma unroll
            for (int mt = 0; mt < 4; ++mt) {
                int row = mt * 16 + lr;
                a[mt] = *(const bf16x8*)&As[row * 128 + (ke ^ ((row & 7) << 3))];
            }
            #pragma unroll
            for (int nt = 0; nt < 4; ++nt)
                b[nt] = *(const bf16x8*)(Bbase + (size_t)(nt * 16 + lr) * 128 + ke);
            #pragma unroll
            for (int nt = 0; nt < 4; ++nt)
                #pragma unroll
                for (int mt = 0; mt < 4; ++mt)
                    acc[nt][mt] = __builtin_amdgcn_mfma_f32_16x16x32_bf16(b[nt], a[mt], acc[nt][mt], 0, 0, 0);
        }

        ushort_t* XW = g_XWx_b[side];
        #pragma unroll
        for (int mt = 0; mt < 4; ++mt) {
            int gm = m0 + mt * 16 + lr;
            if (gm >= M) continue;
            #pragma unroll
            for (int nt = 0; nt < 4; ++nt) {
                int n0 = nbase + nt * 16 + lk * 4;
                f32x4 av = acc[nt][mt];
                uint2 pk;
                pk.x = ((unsigned int)f2bf(av[1]) << 16) | (unsigned int)f2bf(av[0]);
                pk.y = ((unsigned int)f2bf(av[3]) << 16) | (unsigned int)f2bf(av[2]);
                *(uint2*)&XW[(size_t)gm * 256 + n0] = pk;
            }
        }
    } else {
        const ushort_t* QT = &g_QT[layer][0][0];
        f32x4 acc[2][4];
        #pragma unroll
        for (int i = 0; i < 2; ++i)
            #pragma unroll
            for (int j = 0; j < 4; ++j)
                acc[i][j] = (f32x4){0.f, 0.f, 0.f, 0.f};

        #pragma unroll
        for (int ks = 0; ks < 4; ++ks) {
            bf16x8 a[4], b[2];
            int ke = ks * 32 + lk * 8;
            #pragma unroll
            for (int mt = 0; mt < 4; ++mt) {
                int row = mt * 16 + lr;
                a[mt] = *(const bf16x8*)&As[row * 128 + (ke ^ ((row & 7) << 3))];
            }
            #pragma unroll
            for (int nt = 0; nt < 2; ++nt)
                b[nt] = *(const bf16x8*)&QT[(nt * 16 + lr) * 128 + ke];
            #pragma unroll
            for (int nt = 0; nt < 2; ++nt)
                #pragma unroll
                for (int mt = 0; mt < 4; ++mt)
                    acc[nt][mt] = __builtin_amdgcn_mfma_f32_16x16x32_bf16(b[nt], a[mt], acc[nt][mt], 0, 0, 0);
        }

        float* sc = g_scal[side];
        #pragma unroll
        for (int mt = 0; mt < 4; ++mt) {
            int gm = m0 + mt * 16 + lr;
            if (gm >= M) continue;
            #pragma unroll
            for (int nt = 0; nt < 2; ++nt) {
                #pragma unroll
                for (int r = 0; r < 4; ++r) {
                    int colc = nt * 16 + lk * 4 + r;
                    if ((mask >> colc) & 1u)
                        sc[(size_t)gm * 32 + colc] = acc[nt][mt][r];
                }
            }
        }
    }
}

// ------- fused aggregate + inline gate, one node per 16-lane group, both sides -------
__global__ __launch_bounds__(256) void aggregate_kernel(int k, const float* __restrict__ bgi,
                                                        const float* __restrict__ bgo, int N) {
    int side = blockIdx.y;
    int tid = threadIdx.x;
    int wv = tid >> 6;
    int lane = tid & 63;
    int grp = lane >> 4, li = lane & 15;
    int n = blockIdx.x * 16 + wv * 4 + grp;
    bool valid = n < N;
    int cur = k & 1;
    const float* scal = g_scal[side];
    const ushort_t* XW = g_XWx_b[side];

    int pin0 = 0, din = 0, pout0 = 0, dout = 0;
    float cin = 0.f, cout = 0.f;
    if (valid) {
        pin0 = g_off[side][0][n];  din = g_off[side][0][n + 1] - pin0;
        pout0 = g_off[side][1][n]; dout = g_off[side][1][n + 1] - pout0;
        const float* srow = scal + (size_t)n * 32;
        if (k == 0) {
            cin = srow[16]; cout = srow[24];
        } else if (k == 1) {
            cin = srow[18] + srow[19]; cout = srow[26] + srow[27];
        } else {
            cin = srow[20] + srow[21] + srow[22];
            cout = srow[28] + srow[29] + srow[30];
        }
    }
    int tot = din + dout;

    float acc[8];
    {
        float4 b1 = *(const float4*)(bgi + li * 8);
        float4 b2 = *(const float4*)(bgi + li * 8 + 4);
        float4 c1 = *(const float4*)(bgo + li * 8);
        float4 c2 = *(const float4*)(bgo + li * 8 + 4);
        uint4 xv = make_uint4(0u, 0u, 0u, 0u);
        if (valid) xv = *(const uint4*)(g_hb[side][cur] + (size_t)n * 128 + li * 8);
        acc[0] = bflo(xv.x) + b1.x + c1.x;
        acc[1] = bfhi(xv.x) + b1.y + c1.y;
        acc[2] = bflo(xv.y) + b1.z + c1.z;
        acc[3] = bfhi(xv.y) + b1.w + c1.w;
        acc[4] = bflo(xv.z) + b2.x + c2.x;
        acc[5] = bfhi(xv.z) + b2.y + c2.y;
        acc[6] = bflo(xv.w) + b2.z + c2.z;
        acc[7] = bfhi(xv.w) + b2.w + c2.w;
    }

    for (int base = 0; base < tot; base += 16) {
        int cnt = min(16, tot - base);
        float gate = 0.f;
        int sv = 0;
        if (li < cnt) {
            int q = base + li;
            int2 se;
            int dir;
            if (q < din) { se = g_lst[side][0][pin0 + q]; dir = 0; }
            else         { se = g_lst[side][1][pout0 + q - din]; dir = 1; }
            const float* arow = scal + (size_t)se.x * 32 + dir * 8;
            float asum;
            if (k == 0) asum = arow[0];
            else if (k == 1) asum = arow[2] + arow[3];
            else asum = arow[4] + arow[5] + arow[6];
            float s = g_bias[se.y][dir * 3 + k] + asum + (dir ? cout : cin);
            gate = 1.0f / (1.0f + __expf(-s));
            sv = se.x * 2 + dir;
        }
        int e = 0;
        for (; e + 2 <= cnt; e += 2) {
            float w0 = __shfl(gate, grp * 16 + e);
            int a0 = __shfl(sv, grp * 16 + e);
            float w1 = __shfl(gate, grp * 16 + e + 1);
            int a1 = __shfl(sv, grp * 16 + e + 1);
            uint4 p0 = *(const uint4*)(XW + (size_t)(a0 >> 1) * 256 + (a0 & 1) * 128 + li * 8);
            uint4 p1 = *(const uint4*)(XW + (size_t)(a1 >> 1) * 256 + (a1 & 1) * 128 + li * 8);
            acc[0] += w0 * bflo(p0.x) + w1 * bflo(p1.x);
            acc[1] += w0 * bfhi(p0.x) + w1 * bfhi(p1.x);
            acc[2] += w0 * bflo(p0.y) + w1 * bflo(p1.y);
            acc[3] += w0 * bfhi(p0.y) + w1 * bfhi(p1.y);
            acc[4] += w0 * bflo(p0.z) + w1 * bflo(p1.z);
            acc[5] += w0 * bfhi(p0.z) + w1 * bfhi(p1.z);
            acc[6] += w0 * bflo(p0.w) + w1 * bflo(p1.w);
            acc[7] += w0 * bfhi(p0.w) + w1 * bfhi(p1.w);
        }
        if (e < cnt) {
            float w0 = __shfl(gate, grp * 16 + e);
            int a0 = __shfl(sv, grp * 16 + e);
            uint4 p0 = *(const uint4*)(XW + (size_t)(a0 >> 1) * 256 + (a0 & 1) * 128 + li * 8);
            acc[0] += w0 * bflo(p0.x);
            acc[1] += w0 * bfhi(p0.x);
            acc[2] += w0 * bflo(p0.y);
            acc[3] += w0 * bfhi(p0.y);
            acc[4] += w0 * bflo(p0.z);
            acc[5] += w0 * bfhi(p0.z);
            acc[6] += w0 * bflo(p0.w);
            acc[7] += w0 * bfhi(p0.w);
        }
    }

    if (valid) {
        uint4 pk;
        pk.x = ((unsigned int)f2bf(acc[1]) << 16) | (unsigned int)f2bf(acc[0]);
        pk.y = ((unsigned int)f2bf(acc[3]) << 16) | (unsigned int)f2bf(acc[2]);
        pk.z = ((unsigned int)f2bf(acc[5]) << 16) | (unsigned int)f2bf(acc[4]);
        pk.w = ((unsigned int)f2bf(acc[7]) << 16) | (unsigned int)f2bf(acc[6]);
        *(uint4*)(g_hb[side][cur ^ 1] + (size_t)n * 128 + li * 8) = pk;
    }
}

// ---------------- mean-pool partials, both sides ----------------
__global__ void pool_kernel(const int* __restrict__ batch_s, const int* __restrict__ batch_t,
                            int N) {
    int side = blockIdx.y;
    const int* batch = side ? batch_t : batch_s;
    const ushort_t* x = g_hb[side][K_LAYERS & 1];
    float* gsum = g_gsum[side];
    int n0 = blockIdx.x * 128;
    int d = threadIdx.x;
    if (n0 >= N) return;
    int nend = min(n0 + 128, N);
    float acc = 0.f;
    int curg = batch[n0];
    for (int n = n0; n < nend; ++n) {
        int g = batch[n];
        if (g != curg) {
            atomicAdd(&gsum[curg * 128 + d], acc);
            acc = 0.f;
            curg = g;
        }
        acc += bf2f(x[(size_t)n * 128 + d]);
    }
    atomicAdd(&gsum[curg * 128 + d], acc);
}

__global__ void count_kernel(const int* __restrict__ batch_s, const int* __restrict__ batch_t,
                             int N) {
    int side = blockIdx.x;
    const int* batch = side ? batch_t : batch_s;
    int g = threadIdx.x;  // 128
    int lo = 0, hi = N;
    while (lo < hi) { int mid = (lo + hi) >> 1; if (batch[mid] < g) lo = mid + 1; else hi = mid; }
    int a = lo;
    lo = 0; hi = N;
    while (lo < hi) { int mid = (lo + hi) >> 1; if (batch[mid] < g + 1) lo = mid + 1; else hi = mid; }
    g_cnt[side][g] = (float)(lo - a);
}

// ---------------- classifier ----------------
__global__ void hidden_kernel(const float* __restrict__ W0, const float* __restrict__ b0) {
    int g = blockIdx.x;
    int j = threadIdx.x;
    float inv_s = 1.0f / fmaxf(g_cnt[0][g], 1.0f);
    float inv_t = 1.0f / fmaxf(g_cnt[1][g], 1.0f);
    float acc = b0[j];
    for (int k = 0; k < 128; ++k) acc += g_gsum[0][g * 128 + k] * inv_s * W0[k * 128 + j];
    for (int k = 0; k < 128; ++k) acc += g_gsum[1][g * 128 + k] * inv_t * W0[(128 + k) * 128 + j];
    g_H[g * 128 + j] = fmaxf(acc, 0.f);
}

__global__ void loss_kernel(const float* __restrict__ W1, const float* __restrict__ b1,
                            const int* __restrict__ y, float* __restrict__ out) {
    int g = threadIdx.x;
    float l0 = b1[0], l1 = b1[1];
    for (int j = 0; j < 128; ++j) {
        float hv = g_H[g * 128 + j];
        l0 += hv * W1[j * 2 + 0];
        l1 += hv * W1[j * 2 + 1];
    }
    float m = fmaxf(l0, l1);
    float lse = m + logf(expf(l0 - m) + expf(l1 - m));
    float ly = (y[g] == 0) ? l0 : l1;
    float c = -(ly - lse) * (1.0f / (float)N_GRAPHS);
    __shared__ float red[128];
    red[g] = c;
    __syncthreads();
    for (int s = 64; s; s >>= 1) {
        if (g < s) red[g] += red[g + s];
        __syncthreads();
    }
    if (g == 0) out[0] = red[0];
}

extern "C" void kernel_launch(void* const* d_in, const int* in_sizes, int n_in,
                              void* d_out, int out_size, void* d_ws, size_t ws_size,
                              hipStream_t stream) {
    const float* x_s      = (const float*)d_in[0];
    const float* x_t      = (const float*)d_in[1];
    const float* ea_s     = (const float*)d_in[2];
    const float* ea_t     = (const float*)d_in[3];
    const int*   ei_s     = (const int*)d_in[4];
    const int*   ei_t     = (const int*)d_in[5];
    const int*   batch_s  = (const int*)d_in[6];
    const int*   batch_t  = (const int*)d_in[7];
    const int*   y        = (const int*)d_in[8];
    const float* node_emb = (const float*)d_in[9];
    const float* edge_emb = (const float*)d_in[10];
    const float* W_in_0   = (const float*)d_in[11];
    const float* W_in_1   = (const float*)d_in[12];
    const float* W_out_0  = (const float*)d_in[13];
    const float* W_out_1  = (const float*)d_in[14];
    const float* Wg_in    = (const float*)d_in[15];
    const float* bg_in    = (const float*)d_in[16];
    const float* Wg_out   = (const float*)d_in[17];
    const float* bg_out   = (const float*)d_in[18];
    const float* cls_W0   = (const float*)d_in[19];
    const float* cls_b0   = (const float*)d_in[20];
    const float* cls_W1   = (const float*)d_in[21];
    const float* cls_b1   = (const float*)d_in[22];

    const int N = N_NODES, E = N_EDGES;
    static const unsigned int MASKS[3] = {MASK_J0, MASK_J1, MASK_J2};

    zero_misc_kernel<<<(2 * N_GRAPHS * NODE_DIM + 255) / 256, 256, 0, stream>>>();
    setup_gates_kernel<<<6, 128, 0, stream>>>(W_in_0, W_in_1, W_out_0, W_out_1, edge_emb);
    assemble_wcat_all<<<(K_LAYERS * 32768 + 255) / 256, 256, 0, stream>>>(Wg_in, Wg_out);

    node_embed_kernel<<<dim3((N + 3) / 4, 2), 256, 0, stream>>>(x_s, x_t, node_emb, N);
    edge_voc_kernel<<<dim3((2 * E + 255) / 256, 2), 256, 0, stream>>>(ea_s, ea_t, 2 * E);

    csr_zero_kernel<<<(4 * N + 255) / 256, 256, 0, stream>>>();
    csr_count_kernel<<<dim3((E + 255) / 256, 2), 256, 0, stream>>>(ei_s, ei_t, E);
    csr_bsum_kernel<<<dim3(SCAN_NBLK, 2, 2), 256, 0, stream>>>();
    csr_bscan_kernel<<<dim3(2, 2), 64, 0, stream>>>();
    csr_off_kernel<<<dim3(SCAN_NBLK, 2, 2), 256, 0, stream>>>(E);
    csr_fill_kernel<<<dim3((E + 255) / 256, 2), 256, 0, stream>>>(ei_s, ei_t, E);

    for (int k = 0; k < K_LAYERS; ++k) {
        gemm_xw_mfma<<<dim3(GEMM_NB, 2), 320, 0, stream>>>(k, MASKS[k], N);
        aggregate_kernel<<<dim3((N + 15) / 16, 2), 256, 0, stream>>>(
            k, bg_in + (size_t)k * 128, bg_out + (size_t)k * 128, N);
    }

    pool_kernel<<<dim3((N + 127) / 128, 2), 128, 0, stream>>>(batch_s, batch_t, N);
    count_kernel<<<2, 128, 0, stream>>>(batch_s, batch_t, N);

    hidden_kernel<<<128, 128, 0, stream>>>(cls_W0, cls_b0);
    loss_kernel<<<1, 128, 0, stream>>>(cls_W1, cls_b1, y, (float*)d_out);
}